// Round 14
// baseline (374.199 us; speedup 1.0000x reference)
//
#include <hip/hip_runtime.h>
#include <math.h>

#define CDIV(a, b) (((a) + (b) - 1) / (b))

#define LOG2E 1.4426950408889634f
#define SC5  (0.44721359549996f * LOG2E)
#define SC10 (0.31622776601684f * LOG2E)
#define SC21 (0.21821789023599f * LOG2E)
#define EXP2(x) __builtin_amdgcn_exp2f(x)

// ---------- fused 3x3 s2 conv + relu + qkv projection ----------
// block handles TPX pixels of one batch: conv -> LDS + global z, then qkv from LDS.
// q written padded [bh][n][DP]; K/V interleaved per row: kv[bh][n][2*DP] = K(DP)|V(DP).
template <int CIN, int HIN, int COUT, int HOUT, int INNER, int DP, int TPX>
__global__ void __launch_bounds__(256) conv_qkv(const float* __restrict__ in,
                                                const float* __restrict__ cw,
                                                const float* __restrict__ cb,
                                                const float* __restrict__ qw,
                                                const float* __restrict__ qb,
                                                float* __restrict__ z, float* __restrict__ q,
                                                float* __restrict__ kv) {
    constexpr int N = HOUT * HOUT;
    __shared__ float zt[COUT * TPX];
    const int b  = blockIdx.x / (N / TPX);
    const int n0 = (blockIdx.x % (N / TPX)) * TPX;
    const int tid = threadIdx.x;

    // phase 1: conv outputs for this tile (c-major, px fastest -> coalesced z writes)
    for (int idx = tid; idx < COUT * TPX; idx += 256) {
        int c = idx / TPX, px = idx % TPX;
        int n = n0 + px;
        int ho = n / HOUT, wo = n % HOUT;
        float acc = cb[c];
        for (int ci = 0; ci < CIN; ++ci) {
            const float* ip = in + (size_t)(b * CIN + ci) * HIN * HIN;
            const float* wp = cw + (size_t)(c * CIN + ci) * 9;
            #pragma unroll
            for (int kh = 0; kh < 3; ++kh) {
                int hi = 2 * ho + kh - 1;
                if (hi < 0 || hi >= HIN) continue;
                #pragma unroll
                for (int kw = 0; kw < 3; ++kw) {
                    int wi = 2 * wo + kw - 1;
                    if (wi < 0 || wi >= HIN) continue;
                    acc = fmaf(wp[kh * 3 + kw], ip[hi * HIN + wi], acc);
                }
            }
        }
        acc = fmaxf(acc, 0.f);
        zt[idx] = acc;
        z[((size_t)(b * COUT) + c) * N + n] = acc;
    }
    __syncthreads();

    // phase 2: qkv from LDS tile (w reads wave-uniform -> scalar loads)
    constexpr int OC3 = 3 * INNER;
    for (int idx = tid; idx < OC3 * TPX; idx += 256) {
        int oc = idx / TPX, px = idx % TPX;
        float val = qb[oc];
        const float* wp = qw + (size_t)oc * COUT;
        #pragma unroll 8
        for (int c = 0; c < COUT; ++c) val = fmaf(wp[c], zt[c * TPX + px], val);
        int part = oc / INNER;
        int r = oc - part * INNER;
        int hh = r % 3, dd = r / 3;  // heads fastest
        size_t n = n0 + px;
        if (part == 0)
            q[((size_t)(b * 3 + hh) * N + n) * DP + dd] = val;
        else
            kv[((size_t)(b * 3 + hh) * N + n) * (2 * DP) + (part - 1) * DP + dd] = val;
    }
}

// ---------- attention (L1/L2): no-max softmax via native exp2; KV interleaved rows ----------
// grid = 96*IC (bh = blockIdx%96); 4-wave j-split; RPT rows/thread; PF-deep register
// prefetch of KV rows from global (loads stay in flight across compute); LDS combine.
template <int D, int DP, int RPT, int PF>
__global__ void __launch_bounds__(256) attn_big(const float* __restrict__ q,
                                                const float* __restrict__ kv,
                                                const float* __restrict__ table,
                                                float* __restrict__ o, int N, int log2Hg,
                                                int T, float scale2) {
    extern __shared__ float smem[];
    float* tb = smem;    // T floats, pre-scaled by scale2 (incl. log2e)
    float* comb = smem;  // overlays tb after j-loop
    constexpr int ROWS = 64 * RPT;
    constexpr int CSTR = (D % 2 == 0) ? (D + 3) : (D + 2);
    constexpr int NV4 = DP / 4;      // float4 per K (or V) row
    constexpr int RV4 = 2 * NV4;     // float4 per interleaved KV row

    const int bh = blockIdx.x % 96;
    const int chunk = blockIdx.x / 96;
    const int h = bh % 3;
    const int tid = threadIdx.x;
    const int wave = tid >> 6;
    const int lane = tid & 63;
    const int Hg = 1 << log2Hg;
    const int W2 = 2 * Hg - 1;
    const int base = chunk * ROWS;

    for (int t = tid; t < T; t += 256) tb[t] = table[t * 3 + h] * scale2;

    float qr[RPT][D];
    int ibase[RPT];
    #pragma unroll
    for (int r = 0; r < RPT; ++r) {
        int i = base + lane + 64 * r;
        const float* qg = q + ((size_t)bh * N + i) * DP;
        #pragma unroll
        for (int dd = 0; dd < D; ++dd) qr[r][dd] = qg[dd];
        ibase[r] = ((i >> log2Hg) + Hg - 1) * W2 + (i & (Hg - 1)) + Hg - 1;
    }
    __syncthreads();

    float acc[RPT][D];
    float lsum[RPT];
    #pragma unroll
    for (int r = 0; r < RPT; ++r) {
        lsum[r] = 0.f;
        #pragma unroll
        for (int dd = 0; dd < D; ++dd) acc[r][dd] = 0.f;
    }

    const float4* kvb = (const float4*)(kv + (size_t)bh * N * (2 * DP));
    const int NJ = N >> 2;
    const int j0 = wave * NJ;

    float4 buf[PF][RV4];
    #pragma unroll
    for (int p = 0; p < PF; ++p)
        #pragma unroll
        for (int x = 0; x < RV4; ++x) buf[p][x] = kvb[(size_t)(j0 + p) * RV4 + x];

    for (int jj = 0; jj < NJ; jj += PF) {
        #pragma unroll
        for (int p = 0; p < PF; ++p) {
            const int j = j0 + jj + p;
            const float* kr = (const float*)&buf[p][0];
            const float* vr = kr + DP;
            const int joff = (j >> log2Hg) * W2 + (j & (Hg - 1));
            #pragma unroll
            for (int r = 0; r < RPT; ++r) {
                float s = 0.f;
                #pragma unroll
                for (int dd = 0; dd < D; ++dd) s = fmaf(qr[r][dd], kr[dd], s);
                float e = EXP2(fmaf(s, scale2, tb[ibase[r] - joff]));
                lsum[r] += e;
                #pragma unroll
                for (int dd = 0; dd < D; ++dd) acc[r][dd] = fmaf(e, vr[dd], acc[r][dd]);
            }
            // refill slot p with row j+PF (benign over-read; stays inside workspace)
            #pragma unroll
            for (int x = 0; x < RV4; ++x) buf[p][x] = kvb[(size_t)(j + PF) * RV4 + x];
        }
    }

    __syncthreads();
    #pragma unroll
    for (int r = 0; r < RPT; ++r) {
        float* cp = comb + (size_t)(wave * ROWS + lane + 64 * r) * CSTR;
        #pragma unroll
        for (int dd = 0; dd < D; ++dd) cp[dd] = acc[r][dd];
        cp[D] = lsum[r];
    }
    __syncthreads();
    if (tid < ROWS) {
        float af[D];
        #pragma unroll
        for (int dd = 0; dd < D; ++dd) af[dd] = 0.f;
        float lf = 0.f;
        #pragma unroll
        for (int wv = 0; wv < 4; ++wv) {
            const float* cp = comb + (size_t)(wv * ROWS + tid) * CSTR;
            #pragma unroll
            for (int dd = 0; dd < D; ++dd) af[dd] += cp[dd];
            lf += cp[D];
        }
        float inv = 1.0f / lf;
        int i = base + tid;
        #pragma unroll
        for (int dd = 0; dd < D; ++dd)
            o[((size_t)bh * D + dd) * N + i] = af[dd] * inv;  // O layout [bh][d][N]
    }
}

// ---------- L3 attention: one block per bh; KV+table staged in LDS; 4-wave j-split ----------
__global__ void __launch_bounds__(256) attn_small(const float* __restrict__ q,
                                                  const float* __restrict__ kv,
                                                  const float* __restrict__ table,
                                                  float* __restrict__ o, float scale2) {
    constexpr int D = 21, DP = 24, NN = 64;
    constexpr int CSTR = 23;  // odd stride for combine
    __shared__ float smem[4 * NN * CSTR];  // 23552 B; comb overlays kvs/tb
    float* kvs = smem;                 // NN * 2*DP = 3072 floats
    float* tb = kvs + NN * 2 * DP;     // 225
    float* comb = smem;

    const int bh = blockIdx.x;     // 96 blocks
    const int h = bh % 3;
    const int tid = threadIdx.x;
    const int wave = tid >> 6;
    const int lane = tid & 63;

    {
        const float4* kvg = (const float4*)(kv + (size_t)bh * NN * 2 * DP);
        float4* kvs4 = (float4*)kvs;
        for (int t = tid; t < NN * 2 * DP / 4; t += 256) kvs4[t] = kvg[t];
        for (int t = tid; t < 225; t += 256) tb[t] = table[t * 3 + h] * scale2;
    }

    const int i = lane;
    const float* qg = q + ((size_t)bh * NN + i) * DP;
    float qr[D];
    #pragma unroll
    for (int dd = 0; dd < D; ++dd) qr[dd] = qg[dd];
    const int ibase = ((i >> 3) + 7) * 15 + (i & 7) + 7;
    __syncthreads();

    float acc[D];
    #pragma unroll
    for (int dd = 0; dd < D; ++dd) acc[dd] = 0.f;
    float lsum = 0.f;

    const int j0 = wave * 16;
    #pragma unroll
    for (int jj = 0; jj < 16; ++jj) {
        const int j = j0 + jj;
        float4 r4[12];
        const float4* rp = (const float4*)(kvs + j * 2 * DP);
        #pragma unroll
        for (int x = 0; x < 12; ++x) r4[x] = rp[x];
        const float* kr = (const float*)r4;
        const float* vr = kr + DP;
        const int joff = (j >> 3) * 15 + (j & 7);
        float s = 0.f;
        #pragma unroll
        for (int dd = 0; dd < D; ++dd) s = fmaf(qr[dd], kr[dd], s);
        float e = EXP2(fmaf(s, scale2, tb[ibase - joff]));
        lsum += e;
        #pragma unroll
        for (int dd = 0; dd < D; ++dd) acc[dd] = fmaf(e, vr[dd], acc[dd]);
    }

    __syncthreads();
    {
        float* cp = comb + (size_t)(wave * NN + lane) * CSTR;
        #pragma unroll
        for (int dd = 0; dd < D; ++dd) cp[dd] = acc[dd];
        cp[D] = lsum;
    }
    __syncthreads();
    if (tid < NN) {
        float af[D];
        #pragma unroll
        for (int dd = 0; dd < D; ++dd) af[dd] = 0.f;
        float lf = 0.f;
        #pragma unroll
        for (int wv = 0; wv < 4; ++wv) {
            const float* cp = comb + (size_t)(wv * NN + tid) * CSTR;
            #pragma unroll
            for (int dd = 0; dd < D; ++dd) af[dd] += cp[dd];
            lf += cp[D];
        }
        float inv = 1.0f / lf;
        #pragma unroll
        for (int dd = 0; dd < D; ++dd)
            o[((size_t)bh * D + dd) * NN + tid] = af[dd] * inv;
    }
}

// ---------- output projection + bias + residual (exact grid); o layout [bh][d][N] ----------
__global__ void __launch_bounds__(256) outproj(const float* __restrict__ o,
                                               const float* __restrict__ w,
                                               const float* __restrict__ bias,
                                               const float* __restrict__ zin,
                                               float* __restrict__ zout,
                                               int dim, int inner, int N, int d) {
    int t = blockIdx.x * 256 + threadIdx.x;
    int n = t % N;
    int c = (t / N) % dim;
    int b = t / (N * dim);
    float val = bias[c] + zin[t];
    const float* wp = w + (size_t)c * inner;
    for (int dd = 0; dd < d; ++dd) {
        #pragma unroll
        for (int hh = 0; hh < 3; ++hh) {
            val = fmaf(wp[dd * 3 + hh], o[((size_t)((b * 3 + hh) * d) + dd) * N + n], val);
        }
    }
    zout[t] = val;
}

// ---------- tail: outproj3 + global-avg-pool + classifier, one block per batch ----------
__global__ void __launch_bounds__(256) tail(const float* __restrict__ o,
                                            const float* __restrict__ ow,
                                            const float* __restrict__ ob,
                                            const float* __restrict__ zin,
                                            const float* __restrict__ cw,
                                            const float* __restrict__ cb,
                                            float* __restrict__ out) {
    __shared__ float zt[64 * 65];
    __shared__ float p[64];
    const int b = blockIdx.x;
    const int tid = threadIdx.x;
    for (int idx = tid; idx < 64 * 64; idx += 256) {
        int c = idx >> 6, n = idx & 63;
        float val = ob[c] + zin[((size_t)(b * 64) + c) * 64 + n];
        const float* wp = ow + (size_t)c * 63;
        for (int dd = 0; dd < 21; ++dd) {
            #pragma unroll
            for (int hh = 0; hh < 3; ++hh)
                val = fmaf(wp[dd * 3 + hh], o[((size_t)((b * 3 + hh) * 21) + dd) * 64 + n], val);
        }
        zt[c * 65 + n] = val;
    }
    __syncthreads();
    if (tid < 64) {
        float s = 0.f;
        #pragma unroll
        for (int n = 0; n < 64; ++n) s += zt[tid * 65 + n];
        s *= (1.0f / 64.0f);
        p[tid] = s;
        out[b * 64 + tid] = s;
    }
    __syncthreads();
    if (tid < 10) {
        float val = cb[tid];
        const float* wp = cw + (size_t)tid * 64;
        #pragma unroll
        for (int kk = 0; kk < 64; ++kk) val = fmaf(wp[kk], p[kk], val);
        out[2048 + b * 10 + tid] = val;
    }
}

extern "C" void kernel_launch(void* const* d_in, const int* in_sizes, int n_in,
                              void* d_out, int out_size, void* d_ws, size_t ws_size,
                              hipStream_t stream) {
    float* ws = (float*)d_ws;
    float* Z0 = ws;                // conv z (residual input)
    float* Z1 = Z0 + 524288;       // outproj result / next conv input
    float* Q  = Z1 + 524288;       // 786432 (96*1024*8 max)
    float* KV = Q + 786432;        // 1572864 (96*1024*16 max, K|V interleaved per row)
    float* O  = KV + 1572864;      // 491520

    float* out = (float*)d_out;

    // ===== layer 1: Cin=1 H64->32, dim=16, inner=15, d=5 (DP=8), N=1024, Hg=32 =====
    conv_qkv<1, 64, 16, 32, 15, 8, 64><<<32 * 16, 256, 0, stream>>>(
        (const float*)d_in[0], (const float*)d_in[1], (const float*)d_in[2],
        (const float*)d_in[3], (const float*)d_in[4], Z0, Q, KV);
    // LDS = max(T=3969, comb 4*128*7=3584)*4 = 15876 B.  PF=4: ~128cyc lookahead/wave.
    attn_big<5, 8, 2, 4><<<96 * 8, 256, 15876, stream>>>(
        Q, KV, (const float*)d_in[7], O, 1024, 5, 3969, SC5);
    outproj<<<2048, 256, 0, stream>>>(
        O, (const float*)d_in[5], (const float*)d_in[6], Z0, Z1, 16, 15, 1024, 5);

    // ===== layer 2: Cin=16 H32->16, dim=32, inner=30, d=10 (DP=12), N=256, Hg=16 =====
    conv_qkv<16, 32, 32, 16, 30, 12, 32><<<32 * 8, 256, 0, stream>>>(
        Z1, (const float*)d_in[8], (const float*)d_in[9],
        (const float*)d_in[10], (const float*)d_in[11], Z0, Q, KV);
    // LDS = max(T=961, comb 4*64*13=3328)*4 = 13312 B
    attn_big<10, 12, 1, 4><<<96 * 4, 256, 13312, stream>>>(
        Q, KV, (const float*)d_in[14], O, 256, 4, 961, SC10);
    outproj<<<1024, 256, 0, stream>>>(
        O, (const float*)d_in[12], (const float*)d_in[13], Z0, Z1, 32, 30, 256, 10);

    // ===== layer 3: Cin=32 H16->8, dim=64, inner=63, d=21 (DP=24), N=64, Hg=8 =====
    conv_qkv<32, 16, 64, 8, 63, 24, 8><<<32 * 8, 256, 0, stream>>>(
        Z1, (const float*)d_in[15], (const float*)d_in[16],
        (const float*)d_in[17], (const float*)d_in[18], Z0, Q, KV);
    attn_small<<<96, 256, 0, stream>>>(Q, KV, (const float*)d_in[21], O, SC21);
    tail<<<32, 256, 0, stream>>>(
        O, (const float*)d_in[19], (const float*)d_in[20], Z0,
        (const float*)d_in[22], (const float*)d_in[23], out);
}

// Round 15
// 358.681 us; speedup vs baseline: 1.0433x; 1.0433x over previous
//
#include <hip/hip_runtime.h>
#include <math.h>

#define CDIV(a, b) (((a) + (b) - 1) / (b))

#define LOG2E 1.4426950408889634f
#define SC5  (0.44721359549996f * LOG2E)
#define SC10 (0.31622776601684f * LOG2E)
#define SC21 (0.21821789023599f * LOG2E)
#define EXP2(x) __builtin_amdgcn_exp2f(x)

// ---------- fused 3x3 s2 conv + relu + qkv projection ----------
// block handles TPX pixels of one batch: conv -> LDS + global z, then qkv from LDS.
// q written padded [bh][n][DP]; K/V interleaved per row: kv[bh][n][2*DP] = K(DP)|V(DP).
template <int CIN, int HIN, int COUT, int HOUT, int INNER, int DP, int TPX>
__global__ void __launch_bounds__(256) conv_qkv(const float* __restrict__ in,
                                                const float* __restrict__ cw,
                                                const float* __restrict__ cb,
                                                const float* __restrict__ qw,
                                                const float* __restrict__ qb,
                                                float* __restrict__ z, float* __restrict__ q,
                                                float* __restrict__ kv) {
    constexpr int N = HOUT * HOUT;
    __shared__ float zt[COUT * TPX];
    const int b  = blockIdx.x / (N / TPX);
    const int n0 = (blockIdx.x % (N / TPX)) * TPX;
    const int tid = threadIdx.x;

    // phase 1: conv outputs for this tile (c-major, px fastest -> coalesced z writes)
    for (int idx = tid; idx < COUT * TPX; idx += 256) {
        int c = idx / TPX, px = idx % TPX;
        int n = n0 + px;
        int ho = n / HOUT, wo = n % HOUT;
        float acc = cb[c];
        for (int ci = 0; ci < CIN; ++ci) {
            const float* ip = in + (size_t)(b * CIN + ci) * HIN * HIN;
            const float* wp = cw + (size_t)(c * CIN + ci) * 9;
            #pragma unroll
            for (int kh = 0; kh < 3; ++kh) {
                int hi = 2 * ho + kh - 1;
                if (hi < 0 || hi >= HIN) continue;
                #pragma unroll
                for (int kw = 0; kw < 3; ++kw) {
                    int wi = 2 * wo + kw - 1;
                    if (wi < 0 || wi >= HIN) continue;
                    acc = fmaf(wp[kh * 3 + kw], ip[hi * HIN + wi], acc);
                }
            }
        }
        acc = fmaxf(acc, 0.f);
        zt[idx] = acc;
        z[((size_t)(b * COUT) + c) * N + n] = acc;
    }
    __syncthreads();

    // phase 2: qkv from LDS tile (w reads wave-uniform -> scalar loads)
    constexpr int OC3 = 3 * INNER;
    for (int idx = tid; idx < OC3 * TPX; idx += 256) {
        int oc = idx / TPX, px = idx % TPX;
        float val = qb[oc];
        const float* wp = qw + (size_t)oc * COUT;
        #pragma unroll 8
        for (int c = 0; c < COUT; ++c) val = fmaf(wp[c], zt[c * TPX + px], val);
        int part = oc / INNER;
        int r = oc - part * INNER;
        int hh = r % 3, dd = r / 3;  // heads fastest
        size_t n = n0 + px;
        if (part == 0)
            q[((size_t)(b * 3 + hh) * N + n) * DP + dd] = val;
        else
            kv[((size_t)(b * 3 + hh) * N + n) * (2 * DP) + (part - 1) * DP + dd] = val;
    }
}

// ---------- attention (L1/L2): no-max softmax via native exp2; KV interleaved rows ----------
// grid = 96*IC (bh = blockIdx%96); NW-wave j-split (block = NW*64 threads); RPT rows/thread;
// PF-deep register prefetch of KV rows (loads in flight across compute); LDS combine.
template <int D, int DP, int RPT, int PF, int NW>
__global__ void __launch_bounds__(NW * 64) attn_big(const float* __restrict__ q,
                                                    const float* __restrict__ kv,
                                                    const float* __restrict__ table,
                                                    float* __restrict__ o, int N, int log2Hg,
                                                    int T, float scale2) {
    extern __shared__ float smem[];
    float* tb = smem;    // T floats, pre-scaled by scale2 (incl. log2e)
    float* comb = smem;  // overlays tb after j-loop
    constexpr int BT = NW * 64;
    constexpr int ROWS = 64 * RPT;
    constexpr int CSTR = (D % 2 == 0) ? (D + 3) : (D + 2);
    constexpr int NV4 = DP / 4;      // float4 per K (or V) row
    constexpr int RV4 = 2 * NV4;     // float4 per interleaved KV row

    const int bh = blockIdx.x % 96;
    const int chunk = blockIdx.x / 96;
    const int h = bh % 3;
    const int tid = threadIdx.x;
    const int wave = tid >> 6;
    const int lane = tid & 63;
    const int Hg = 1 << log2Hg;
    const int W2 = 2 * Hg - 1;
    const int base = chunk * ROWS;

    for (int t = tid; t < T; t += BT) tb[t] = table[t * 3 + h] * scale2;

    float qr[RPT][D];
    int ibase[RPT];
    #pragma unroll
    for (int r = 0; r < RPT; ++r) {
        int i = base + lane + 64 * r;
        const float* qg = q + ((size_t)bh * N + i) * DP;
        #pragma unroll
        for (int dd = 0; dd < D; ++dd) qr[r][dd] = qg[dd];
        ibase[r] = ((i >> log2Hg) + Hg - 1) * W2 + (i & (Hg - 1)) + Hg - 1;
    }
    __syncthreads();

    float acc[RPT][D];
    float lsum[RPT];
    #pragma unroll
    for (int r = 0; r < RPT; ++r) {
        lsum[r] = 0.f;
        #pragma unroll
        for (int dd = 0; dd < D; ++dd) acc[r][dd] = 0.f;
    }

    const float4* kvb = (const float4*)(kv + (size_t)bh * N * (2 * DP));
    const int NJ = N / NW;
    const int j0 = wave * NJ;

    float4 buf[PF][RV4];
    #pragma unroll
    for (int p = 0; p < PF; ++p)
        #pragma unroll
        for (int x = 0; x < RV4; ++x) buf[p][x] = kvb[(size_t)(j0 + p) * RV4 + x];

    for (int jj = 0; jj < NJ; jj += PF) {
        #pragma unroll
        for (int p = 0; p < PF; ++p) {
            const int j = j0 + jj + p;
            const float* kr = (const float*)&buf[p][0];
            const float* vr = kr + DP;
            const int joff = (j >> log2Hg) * W2 + (j & (Hg - 1));
            #pragma unroll
            for (int r = 0; r < RPT; ++r) {
                float s = 0.f;
                #pragma unroll
                for (int dd = 0; dd < D; ++dd) s = fmaf(qr[r][dd], kr[dd], s);
                float e = EXP2(fmaf(s, scale2, tb[ibase[r] - joff]));
                lsum[r] += e;
                #pragma unroll
                for (int dd = 0; dd < D; ++dd) acc[r][dd] = fmaf(e, vr[dd], acc[r][dd]);
            }
            // refill slot p with row j+PF (benign over-read; stays inside workspace)
            #pragma unroll
            for (int x = 0; x < RV4; ++x) buf[p][x] = kvb[(size_t)(j + PF) * RV4 + x];
        }
    }

    __syncthreads();
    #pragma unroll
    for (int r = 0; r < RPT; ++r) {
        float* cp = comb + (size_t)(wave * ROWS + lane + 64 * r) * CSTR;
        #pragma unroll
        for (int dd = 0; dd < D; ++dd) cp[dd] = acc[r][dd];
        cp[D] = lsum[r];
    }
    __syncthreads();
    if (tid < ROWS) {
        float af[D];
        #pragma unroll
        for (int dd = 0; dd < D; ++dd) af[dd] = 0.f;
        float lf = 0.f;
        #pragma unroll
        for (int wv = 0; wv < NW; ++wv) {
            const float* cp = comb + (size_t)(wv * ROWS + tid) * CSTR;
            #pragma unroll
            for (int dd = 0; dd < D; ++dd) af[dd] += cp[dd];
            lf += cp[D];
        }
        float inv = 1.0f / lf;
        int i = base + tid;
        #pragma unroll
        for (int dd = 0; dd < D; ++dd)
            o[((size_t)bh * D + dd) * N + i] = af[dd] * inv;  // O layout [bh][d][N]
    }
}

// ---------- L3 attention: one block per bh; KV+table staged in LDS; 4-wave j-split ----------
__global__ void __launch_bounds__(256) attn_small(const float* __restrict__ q,
                                                  const float* __restrict__ kv,
                                                  const float* __restrict__ table,
                                                  float* __restrict__ o, float scale2) {
    constexpr int D = 21, DP = 24, NN = 64;
    constexpr int CSTR = 23;  // odd stride for combine
    __shared__ float smem[4 * NN * CSTR];  // 23552 B; comb overlays kvs/tb
    float* kvs = smem;                 // NN * 2*DP = 3072 floats
    float* tb = kvs + NN * 2 * DP;     // 225
    float* comb = smem;

    const int bh = blockIdx.x;     // 96 blocks
    const int h = bh % 3;
    const int tid = threadIdx.x;
    const int wave = tid >> 6;
    const int lane = tid & 63;

    {
        const float4* kvg = (const float4*)(kv + (size_t)bh * NN * 2 * DP);
        float4* kvs4 = (float4*)kvs;
        for (int t = tid; t < NN * 2 * DP / 4; t += 256) kvs4[t] = kvg[t];
        for (int t = tid; t < 225; t += 256) tb[t] = table[t * 3 + h] * scale2;
    }

    const int i = lane;
    const float* qg = q + ((size_t)bh * NN + i) * DP;
    float qr[D];
    #pragma unroll
    for (int dd = 0; dd < D; ++dd) qr[dd] = qg[dd];
    const int ibase = ((i >> 3) + 7) * 15 + (i & 7) + 7;
    __syncthreads();

    float acc[D];
    #pragma unroll
    for (int dd = 0; dd < D; ++dd) acc[dd] = 0.f;
    float lsum = 0.f;

    const int j0 = wave * 16;
    #pragma unroll
    for (int jj = 0; jj < 16; ++jj) {
        const int j = j0 + jj;
        float4 r4[12];
        const float4* rp = (const float4*)(kvs + j * 2 * DP);
        #pragma unroll
        for (int x = 0; x < 12; ++x) r4[x] = rp[x];
        const float* kr = (const float*)r4;
        const float* vr = kr + DP;
        const int joff = (j >> 3) * 15 + (j & 7);
        float s = 0.f;
        #pragma unroll
        for (int dd = 0; dd < D; ++dd) s = fmaf(qr[dd], kr[dd], s);
        float e = EXP2(fmaf(s, scale2, tb[ibase - joff]));
        lsum += e;
        #pragma unroll
        for (int dd = 0; dd < D; ++dd) acc[dd] = fmaf(e, vr[dd], acc[dd]);
    }

    __syncthreads();
    {
        float* cp = comb + (size_t)(wave * NN + lane) * CSTR;
        #pragma unroll
        for (int dd = 0; dd < D; ++dd) cp[dd] = acc[dd];
        cp[D] = lsum;
    }
    __syncthreads();
    if (tid < NN) {
        float af[D];
        #pragma unroll
        for (int dd = 0; dd < D; ++dd) af[dd] = 0.f;
        float lf = 0.f;
        #pragma unroll
        for (int wv = 0; wv < 4; ++wv) {
            const float* cp = comb + (size_t)(wv * NN + tid) * CSTR;
            #pragma unroll
            for (int dd = 0; dd < D; ++dd) af[dd] += cp[dd];
            lf += cp[D];
        }
        float inv = 1.0f / lf;
        #pragma unroll
        for (int dd = 0; dd < D; ++dd)
            o[((size_t)bh * D + dd) * NN + tid] = af[dd] * inv;
    }
}

// ---------- output projection + bias + residual (exact grid); o layout [bh][d][N] ----------
__global__ void __launch_bounds__(256) outproj(const float* __restrict__ o,
                                               const float* __restrict__ w,
                                               const float* __restrict__ bias,
                                               const float* __restrict__ zin,
                                               float* __restrict__ zout,
                                               int dim, int inner, int N, int d) {
    int t = blockIdx.x * 256 + threadIdx.x;
    int n = t % N;
    int c = (t / N) % dim;
    int b = t / (N * dim);
    float val = bias[c] + zin[t];
    const float* wp = w + (size_t)c * inner;
    for (int dd = 0; dd < d; ++dd) {
        #pragma unroll
        for (int hh = 0; hh < 3; ++hh) {
            val = fmaf(wp[dd * 3 + hh], o[((size_t)((b * 3 + hh) * d) + dd) * N + n], val);
        }
    }
    zout[t] = val;
}

// ---------- tail: outproj3 + global-avg-pool + classifier, one block per batch ----------
__global__ void __launch_bounds__(256) tail(const float* __restrict__ o,
                                            const float* __restrict__ ow,
                                            const float* __restrict__ ob,
                                            const float* __restrict__ zin,
                                            const float* __restrict__ cw,
                                            const float* __restrict__ cb,
                                            float* __restrict__ out) {
    __shared__ float zt[64 * 65];
    __shared__ float p[64];
    const int b = blockIdx.x;
    const int tid = threadIdx.x;
    for (int idx = tid; idx < 64 * 64; idx += 256) {
        int c = idx >> 6, n = idx & 63;
        float val = ob[c] + zin[((size_t)(b * 64) + c) * 64 + n];
        const float* wp = ow + (size_t)c * 63;
        for (int dd = 0; dd < 21; ++dd) {
            #pragma unroll
            for (int hh = 0; hh < 3; ++hh)
                val = fmaf(wp[dd * 3 + hh], o[((size_t)((b * 3 + hh) * 21) + dd) * 64 + n], val);
        }
        zt[c * 65 + n] = val;
    }
    __syncthreads();
    if (tid < 64) {
        float s = 0.f;
        #pragma unroll
        for (int n = 0; n < 64; ++n) s += zt[tid * 65 + n];
        s *= (1.0f / 64.0f);
        p[tid] = s;
        out[b * 64 + tid] = s;
    }
    __syncthreads();
    if (tid < 10) {
        float val = cb[tid];
        const float* wp = cw + (size_t)tid * 64;
        #pragma unroll
        for (int kk = 0; kk < 64; ++kk) val = fmaf(wp[kk], p[kk], val);
        out[2048 + b * 10 + tid] = val;
    }
}

extern "C" void kernel_launch(void* const* d_in, const int* in_sizes, int n_in,
                              void* d_out, int out_size, void* d_ws, size_t ws_size,
                              hipStream_t stream) {
    float* ws = (float*)d_ws;
    float* Z0 = ws;                // conv z (residual input)
    float* Z1 = Z0 + 524288;       // outproj result / next conv input
    float* Q  = Z1 + 524288;       // 786432 (96*1024*8 max)
    float* KV = Q + 786432;        // 1572864 (96*1024*16 max, K|V interleaved per row)
    float* O  = KV + 1572864;      // 491520

    float* out = (float*)d_out;

    // ===== layer 1: Cin=1 H64->32, dim=16, inner=15, d=5 (DP=8), N=1024, Hg=32 =====
    conv_qkv<1, 64, 16, 32, 15, 8, 64><<<32 * 16, 256, 0, stream>>>(
        (const float*)d_in[0], (const float*)d_in[1], (const float*)d_in[2],
        (const float*)d_in[3], (const float*)d_in[4], Z0, Q, KV);
    // 512-thr blocks, 8-wave j-split: 768 blocks -> 24 waves/CU cap (75%).
    // LDS = max(tb 3969, comb 8*128*7=7168)*4 = 28672 B -> 3 blocks/CU = 86 KB.
    attn_big<5, 8, 2, 2, 8><<<96 * 8, 512, 28672, stream>>>(
        Q, KV, (const float*)d_in[7], O, 1024, 5, 3969, SC5);
    outproj<<<2048, 256, 0, stream>>>(
        O, (const float*)d_in[5], (const float*)d_in[6], Z0, Z1, 16, 15, 1024, 5);

    // ===== layer 2: Cin=16 H32->16, dim=32, inner=30, d=10 (DP=12), N=256, Hg=16 =====
    conv_qkv<16, 32, 32, 16, 30, 12, 32><<<32 * 8, 256, 0, stream>>>(
        Z1, (const float*)d_in[8], (const float*)d_in[9],
        (const float*)d_in[10], (const float*)d_in[11], Z0, Q, KV);
    // LDS = max(T=961, comb 4*64*13=3328)*4 = 13312 B
    attn_big<10, 12, 1, 2, 4><<<96 * 4, 256, 13312, stream>>>(
        Q, KV, (const float*)d_in[14], O, 256, 4, 961, SC10);
    outproj<<<1024, 256, 0, stream>>>(
        O, (const float*)d_in[12], (const float*)d_in[13], Z0, Z1, 32, 30, 256, 10);

    // ===== layer 3: Cin=32 H16->8, dim=64, inner=63, d=21 (DP=24), N=64, Hg=8 =====
    conv_qkv<32, 16, 64, 8, 63, 24, 8><<<32 * 8, 256, 0, stream>>>(
        Z1, (const float*)d_in[15], (const float*)d_in[16],
        (const float*)d_in[17], (const float*)d_in[18], Z0, Q, KV);
    attn_small<<<96, 256, 0, stream>>>(Q, KV, (const float*)d_in[21], O, SC21);
    tail<<<32, 256, 0, stream>>>(
        O, (const float*)d_in[19], (const float*)d_in[20], Z0,
        (const float*)d_in[22], (const float*)d_in[23], out);
}

// Round 16
// 327.661 us; speedup vs baseline: 1.1420x; 1.0947x over previous
//
#include <hip/hip_runtime.h>
#include <math.h>

#define CDIV(a, b) (((a) + (b) - 1) / (b))

#define LOG2E 1.4426950408889634f
#define SC5  (0.44721359549996f * LOG2E)
#define SC10 (0.31622776601684f * LOG2E)
#define SC21 (0.21821789023599f * LOG2E)
#define EXP2(x) __builtin_amdgcn_exp2f(x)

// ---------- fused 3x3 s2 conv + relu + qkv projection (layer 1 only) ----------
// q written padded [bh][n][DP]; K/V interleaved per row: kv[bh][n][2*DP] = K(DP)|V(DP).
template <int CIN, int HIN, int COUT, int HOUT, int INNER, int DP, int TPX>
__global__ void __launch_bounds__(256) conv_qkv(const float* __restrict__ in,
                                                const float* __restrict__ cw,
                                                const float* __restrict__ cb,
                                                const float* __restrict__ qw,
                                                const float* __restrict__ qb,
                                                float* __restrict__ z, float* __restrict__ q,
                                                float* __restrict__ kv) {
    constexpr int N = HOUT * HOUT;
    __shared__ float zt[COUT * TPX];
    const int b  = blockIdx.x / (N / TPX);
    const int n0 = (blockIdx.x % (N / TPX)) * TPX;
    const int tid = threadIdx.x;

    for (int idx = tid; idx < COUT * TPX; idx += 256) {
        int c = idx / TPX, px = idx % TPX;
        int n = n0 + px;
        int ho = n / HOUT, wo = n % HOUT;
        float acc = cb[c];
        for (int ci = 0; ci < CIN; ++ci) {
            const float* ip = in + (size_t)(b * CIN + ci) * HIN * HIN;
            const float* wp = cw + (size_t)(c * CIN + ci) * 9;
            #pragma unroll
            for (int kh = 0; kh < 3; ++kh) {
                int hi = 2 * ho + kh - 1;
                if (hi < 0 || hi >= HIN) continue;
                #pragma unroll
                for (int kw = 0; kw < 3; ++kw) {
                    int wi = 2 * wo + kw - 1;
                    if (wi < 0 || wi >= HIN) continue;
                    acc = fmaf(wp[kh * 3 + kw], ip[hi * HIN + wi], acc);
                }
            }
        }
        acc = fmaxf(acc, 0.f);
        zt[idx] = acc;
        z[((size_t)(b * COUT) + c) * N + n] = acc;
    }
    __syncthreads();

    constexpr int OC3 = 3 * INNER;
    for (int idx = tid; idx < OC3 * TPX; idx += 256) {
        int oc = idx / TPX, px = idx % TPX;
        float val = qb[oc];
        const float* wp = qw + (size_t)oc * COUT;
        #pragma unroll 8
        for (int c = 0; c < COUT; ++c) val = fmaf(wp[c], zt[c * TPX + px], val);
        int part = oc / INNER;
        int r = oc - part * INNER;
        int hh = r % 3, dd = r / 3;  // heads fastest
        size_t n = n0 + px;
        if (part == 0)
            q[((size_t)(b * 3 + hh) * N + n) * DP + dd] = val;
        else
            kv[((size_t)(b * 3 + hh) * N + n) * (2 * DP) + (part - 1) * DP + dd] = val;
    }
}

// ---------- fused: prev outproj(+residual) halo -> conv3x3 s2 relu -> qkv ----------
// Each block recomputes the previous layer's outproj output for its conv input halo
// (LDS), avoiding the Z1 global round trip and an entire dispatch. o1 layout [bh][d][N1].
template <int CPREV, int INNERP, int DPREV, int HINW, int COUT, int HOUT, int INNER, int DP, int TPX>
__global__ void __launch_bounds__(256) fused_oc(const float* __restrict__ o1,
                                                const float* __restrict__ ow,
                                                const float* __restrict__ ob,
                                                const float* __restrict__ zres,
                                                const float* __restrict__ cw,
                                                const float* __restrict__ cb,
                                                const float* __restrict__ qw,
                                                const float* __restrict__ qb,
                                                float* __restrict__ z, float* __restrict__ q,
                                                float* __restrict__ kv) {
    constexpr int N2 = HOUT * HOUT;
    constexpr int N1 = HINW * HINW;
    constexpr int TROWS = TPX / HOUT;     // output rows per tile
    constexpr int HR = 2 * TROWS + 1;     // halo input rows
    constexpr int HALO = HR * HINW;
    __shared__ float zh[CPREV * HALO];
    __shared__ float zt[COUT * TPX];
    const int b  = blockIdx.x / (N2 / TPX);
    const int n0 = (blockIdx.x % (N2 / TPX)) * TPX;
    const int tid = threadIdx.x;
    const int ho0 = n0 / HOUT;
    const int row0 = 2 * ho0 - 1;

    // phase 0: previous layer output (outproj + bias + residual) for the halo -> LDS
    for (int t = tid; t < CPREV * HALO; t += 256) {
        int ci = t / HALO, p = t - ci * HALO;
        int r = p / HINW, col = p - r * HINW;
        int row = row0 + r;
        float val = 0.f;  // conv zero-padding
        if (row >= 0 && row < HINW) {
            int n1 = row * HINW + col;
            val = ob[ci] + zres[((size_t)(b * CPREV) + ci) * N1 + n1];
            const float* wp = ow + (size_t)ci * INNERP;
            for (int dd = 0; dd < DPREV; ++dd) {
                #pragma unroll
                for (int hh = 0; hh < 3; ++hh)
                    val = fmaf(wp[dd * 3 + hh],
                               o1[((size_t)((b * 3 + hh) * DPREV) + dd) * N1 + n1], val);
            }
        }
        zh[t] = val;
    }
    __syncthreads();

    // phase 1: conv from LDS halo (+ relu); write z (residual for this layer) + LDS
    for (int idx = tid; idx < COUT * TPX; idx += 256) {
        int c = idx / TPX, px = idx - (idx / TPX) * TPX;
        int hol = px / HOUT, wo = px - hol * HOUT;
        float acc = cb[c];
        for (int ci = 0; ci < CPREV; ++ci) {
            const float* zp = zh + ci * HALO;
            const float* wp = cw + (size_t)(c * CPREV + ci) * 9;
            #pragma unroll
            for (int kh = 0; kh < 3; ++kh) {
                int r = 2 * hol + kh;
                #pragma unroll
                for (int kw = 0; kw < 3; ++kw) {
                    int col = 2 * wo + kw - 1;
                    if (col < 0 || col >= HINW) continue;
                    acc = fmaf(wp[kh * 3 + kw], zp[r * HINW + col], acc);
                }
            }
        }
        acc = fmaxf(acc, 0.f);
        zt[idx] = acc;
        z[((size_t)(b * COUT) + c) * N2 + n0 + px] = acc;
    }
    __syncthreads();

    // phase 2: qkv from LDS tile
    constexpr int OC3 = 3 * INNER;
    for (int idx = tid; idx < OC3 * TPX; idx += 256) {
        int oc = idx / TPX, px = idx % TPX;
        float val = qb[oc];
        const float* wp = qw + (size_t)oc * COUT;
        #pragma unroll 8
        for (int c = 0; c < COUT; ++c) val = fmaf(wp[c], zt[c * TPX + px], val);
        int part = oc / INNER;
        int r = oc - part * INNER;
        int hh = r % 3, dd = r / 3;  // heads fastest
        size_t n = n0 + px;
        if (part == 0)
            q[((size_t)(b * 3 + hh) * N2 + n) * DP + dd] = val;
        else
            kv[((size_t)(b * 3 + hh) * N2 + n) * (2 * DP) + (part - 1) * DP + dd] = val;
    }
}

// ---------- attention (L1/L2): no-max softmax via native exp2; KV interleaved rows ----------
// grid = 96*IC (bh = blockIdx%96); NW-wave j-split; RPT rows/thread; PF-deep register
// prefetch of KV rows (loads in flight across compute); LDS combine (odd stride).
template <int D, int DP, int RPT, int PF, int NW>
__global__ void __launch_bounds__(NW * 64) attn_big(const float* __restrict__ q,
                                                    const float* __restrict__ kv,
                                                    const float* __restrict__ table,
                                                    float* __restrict__ o, int N, int log2Hg,
                                                    int T, float scale2) {
    extern __shared__ float smem[];
    float* tb = smem;    // T floats, pre-scaled by scale2 (incl. log2e)
    float* comb = smem;  // overlays tb after j-loop
    constexpr int BT = NW * 64;
    constexpr int ROWS = 64 * RPT;
    constexpr int CSTR = (D % 2 == 0) ? (D + 3) : (D + 2);
    constexpr int NV4 = DP / 4;
    constexpr int RV4 = 2 * NV4;

    const int bh = blockIdx.x % 96;
    const int chunk = blockIdx.x / 96;
    const int h = bh % 3;
    const int tid = threadIdx.x;
    const int wave = tid >> 6;
    const int lane = tid & 63;
    const int Hg = 1 << log2Hg;
    const int W2 = 2 * Hg - 1;
    const int base = chunk * ROWS;

    for (int t = tid; t < T; t += BT) tb[t] = table[t * 3 + h] * scale2;

    float qr[RPT][D];
    int ibase[RPT];
    #pragma unroll
    for (int r = 0; r < RPT; ++r) {
        int i = base + lane + 64 * r;
        const float* qg = q + ((size_t)bh * N + i) * DP;
        #pragma unroll
        for (int dd = 0; dd < D; ++dd) qr[r][dd] = qg[dd];
        ibase[r] = ((i >> log2Hg) + Hg - 1) * W2 + (i & (Hg - 1)) + Hg - 1;
    }
    __syncthreads();

    float acc[RPT][D];
    float lsum[RPT];
    #pragma unroll
    for (int r = 0; r < RPT; ++r) {
        lsum[r] = 0.f;
        #pragma unroll
        for (int dd = 0; dd < D; ++dd) acc[r][dd] = 0.f;
    }

    const float4* kvb = (const float4*)(kv + (size_t)bh * N * (2 * DP));
    const int NJ = N / NW;
    const int j0 = wave * NJ;

    float4 buf[PF][RV4];
    #pragma unroll
    for (int p = 0; p < PF; ++p)
        #pragma unroll
        for (int x = 0; x < RV4; ++x) buf[p][x] = kvb[(size_t)(j0 + p) * RV4 + x];

    for (int jj = 0; jj < NJ; jj += PF) {
        #pragma unroll
        for (int p = 0; p < PF; ++p) {
            const int j = j0 + jj + p;
            const float* kr = (const float*)&buf[p][0];
            const float* vr = kr + DP;
            const int joff = (j >> log2Hg) * W2 + (j & (Hg - 1));
            #pragma unroll
            for (int r = 0; r < RPT; ++r) {
                float s = 0.f;
                #pragma unroll
                for (int dd = 0; dd < D; ++dd) s = fmaf(qr[r][dd], kr[dd], s);
                float e = EXP2(fmaf(s, scale2, tb[ibase[r] - joff]));
                lsum[r] += e;
                #pragma unroll
                for (int dd = 0; dd < D; ++dd) acc[r][dd] = fmaf(e, vr[dd], acc[r][dd]);
            }
            #pragma unroll
            for (int x = 0; x < RV4; ++x) buf[p][x] = kvb[(size_t)(j + PF) * RV4 + x];
        }
    }

    __syncthreads();
    #pragma unroll
    for (int r = 0; r < RPT; ++r) {
        float* cp = comb + (size_t)(wave * ROWS + lane + 64 * r) * CSTR;
        #pragma unroll
        for (int dd = 0; dd < D; ++dd) cp[dd] = acc[r][dd];
        cp[D] = lsum[r];
    }
    __syncthreads();
    if (tid < ROWS) {
        float af[D];
        #pragma unroll
        for (int dd = 0; dd < D; ++dd) af[dd] = 0.f;
        float lf = 0.f;
        #pragma unroll
        for (int wv = 0; wv < NW; ++wv) {
            const float* cp = comb + (size_t)(wv * ROWS + tid) * CSTR;
            #pragma unroll
            for (int dd = 0; dd < D; ++dd) af[dd] += cp[dd];
            lf += cp[D];
        }
        float inv = 1.0f / lf;
        int i = base + tid;
        #pragma unroll
        for (int dd = 0; dd < D; ++dd)
            o[((size_t)bh * D + dd) * N + i] = af[dd] * inv;  // O layout [bh][d][N]
    }
}

// ---------- L3 attention: one block per bh; KV+table staged in LDS; 4-wave j-split ----------
__global__ void __launch_bounds__(256) attn_small(const float* __restrict__ q,
                                                  const float* __restrict__ kv,
                                                  const float* __restrict__ table,
                                                  float* __restrict__ o, float scale2) {
    constexpr int D = 21, DP = 24, NN = 64;
    constexpr int CSTR = 23;
    __shared__ float smem[4 * NN * CSTR];  // 23552 B; comb overlays kvs/tb
    float* kvs = smem;
    float* tb = kvs + NN * 2 * DP;
    float* comb = smem;

    const int bh = blockIdx.x;     // 96 blocks
    const int h = bh % 3;
    const int tid = threadIdx.x;
    const int wave = tid >> 6;
    const int lane = tid & 63;

    {
        const float4* kvg = (const float4*)(kv + (size_t)bh * NN * 2 * DP);
        float4* kvs4 = (float4*)kvs;
        for (int t = tid; t < NN * 2 * DP / 4; t += 256) kvs4[t] = kvg[t];
        for (int t = tid; t < 225; t += 256) tb[t] = table[t * 3 + h] * scale2;
    }

    const int i = lane;
    const float* qg = q + ((size_t)bh * NN + i) * DP;
    float qr[D];
    #pragma unroll
    for (int dd = 0; dd < D; ++dd) qr[dd] = qg[dd];
    const int ibase = ((i >> 3) + 7) * 15 + (i & 7) + 7;
    __syncthreads();

    float acc[D];
    #pragma unroll
    for (int dd = 0; dd < D; ++dd) acc[dd] = 0.f;
    float lsum = 0.f;

    const int j0 = wave * 16;
    #pragma unroll
    for (int jj = 0; jj < 16; ++jj) {
        const int j = j0 + jj;
        float4 r4[12];
        const float4* rp = (const float4*)(kvs + j * 2 * DP);
        #pragma unroll
        for (int x = 0; x < 12; ++x) r4[x] = rp[x];
        const float* kr = (const float*)r4;
        const float* vr = kr + DP;
        const int joff = (j >> 3) * 15 + (j & 7);
        float s = 0.f;
        #pragma unroll
        for (int dd = 0; dd < D; ++dd) s = fmaf(qr[dd], kr[dd], s);
        float e = EXP2(fmaf(s, scale2, tb[ibase - joff]));
        lsum += e;
        #pragma unroll
        for (int dd = 0; dd < D; ++dd) acc[dd] = fmaf(e, vr[dd], acc[dd]);
    }

    __syncthreads();
    {
        float* cp = comb + (size_t)(wave * NN + lane) * CSTR;
        #pragma unroll
        for (int dd = 0; dd < D; ++dd) cp[dd] = acc[dd];
        cp[D] = lsum;
    }
    __syncthreads();
    if (tid < NN) {
        float af[D];
        #pragma unroll
        for (int dd = 0; dd < D; ++dd) af[dd] = 0.f;
        float lf = 0.f;
        #pragma unroll
        for (int wv = 0; wv < 4; ++wv) {
            const float* cp = comb + (size_t)(wv * NN + tid) * CSTR;
            #pragma unroll
            for (int dd = 0; dd < D; ++dd) af[dd] += cp[dd];
            lf += cp[D];
        }
        float inv = 1.0f / lf;
        #pragma unroll
        for (int dd = 0; dd < D; ++dd)
            o[((size_t)bh * D + dd) * NN + tid] = af[dd] * inv;
    }
}

// ---------- tail: outproj3 + global-avg-pool + classifier, one block per batch ----------
__global__ void __launch_bounds__(256) tail(const float* __restrict__ o,
                                            const float* __restrict__ ow,
                                            const float* __restrict__ ob,
                                            const float* __restrict__ zin,
                                            const float* __restrict__ cw,
                                            const float* __restrict__ cb,
                                            float* __restrict__ out) {
    __shared__ float zt[64 * 65];
    __shared__ float p[64];
    const int b = blockIdx.x;
    const int tid = threadIdx.x;
    for (int idx = tid; idx < 64 * 64; idx += 256) {
        int c = idx >> 6, n = idx & 63;
        float val = ob[c] + zin[((size_t)(b * 64) + c) * 64 + n];
        const float* wp = ow + (size_t)c * 63;
        for (int dd = 0; dd < 21; ++dd) {
            #pragma unroll
            for (int hh = 0; hh < 3; ++hh)
                val = fmaf(wp[dd * 3 + hh], o[((size_t)((b * 3 + hh) * 21) + dd) * 64 + n], val);
        }
        zt[c * 65 + n] = val;
    }
    __syncthreads();
    if (tid < 64) {
        float s = 0.f;
        #pragma unroll
        for (int n = 0; n < 64; ++n) s += zt[tid * 65 + n];
        s *= (1.0f / 64.0f);
        p[tid] = s;
        out[b * 64 + tid] = s;
    }
    __syncthreads();
    if (tid < 10) {
        float val = cb[tid];
        const float* wp = cw + (size_t)tid * 64;
        #pragma unroll
        for (int kk = 0; kk < 64; ++kk) val = fmaf(wp[kk], p[kk], val);
        out[2048 + b * 10 + tid] = val;
    }
}

extern "C" void kernel_launch(void* const* d_in, const int* in_sizes, int n_in,
                              void* d_out, int out_size, void* d_ws, size_t ws_size,
                              hipStream_t stream) {
    float* ws = (float*)d_ws;
    float* Zc1 = ws;                 // conv1 z (524288) / later conv3 z (131072)
    float* Zc2 = Zc1 + 524288;       // conv2 z (262144)
    float* Q   = Zc2 + 262144;       // 786432 (96*1024*8 max)
    float* KV  = Q + 786432;         // 1572864 (96*1024*16 max)
    float* O   = KV + 1572864;       // 491520 (96*1024*5 max)

    float* out = (float*)d_out;

    // ===== layer 1: Cin=1 H64->32, dim=16, inner=15, d=5 (DP=8), N=1024, Hg=32 =====
    conv_qkv<1, 64, 16, 32, 15, 8, 64><<<32 * 16, 256, 0, stream>>>(
        (const float*)d_in[0], (const float*)d_in[1], (const float*)d_in[2],
        (const float*)d_in[3], (const float*)d_in[4], Zc1, Q, KV);
    // R13-best attn config: 256 thr, 4-wave split, PF=2. LDS = max(3969, 4*128*7)*4 = 15876 B
    attn_big<5, 8, 2, 2, 4><<<96 * 8, 256, 15876, stream>>>(
        Q, KV, (const float*)d_in[7], O, 1024, 5, 3969, SC5);

    // ===== layer 2 (fused outproj1 + conv2 + qkv2): dim=32, inner=30, d=10 (DP=12), N=256 =====
    fused_oc<16, 15, 5, 32, 32, 16, 30, 12, 32><<<32 * 8, 256, 0, stream>>>(
        O, (const float*)d_in[5], (const float*)d_in[6], Zc1,
        (const float*)d_in[8], (const float*)d_in[9],
        (const float*)d_in[10], (const float*)d_in[11], Zc2, Q, KV);
    attn_big<10, 12, 1, 2, 4><<<96 * 4, 256, 13312, stream>>>(
        Q, KV, (const float*)d_in[14], O, 256, 4, 961, SC10);

    // ===== layer 3 (fused outproj2 + conv3 + qkv3): dim=64, inner=63, d=21 (DP=24), N=64 =====
    fused_oc<32, 30, 10, 16, 64, 8, 63, 24, 8><<<32 * 8, 256, 0, stream>>>(
        O, (const float*)d_in[12], (const float*)d_in[13], Zc2,
        (const float*)d_in[15], (const float*)d_in[16],
        (const float*)d_in[17], (const float*)d_in[18], Zc1, Q, KV);
    attn_small<<<96, 256, 0, stream>>>(Q, KV, (const float*)d_in[21], O, SC21);

    // ===== head =====
    tail<<<32, 256, 0, stream>>>(
        O, (const float*)d_in[19], (const float*)d_in[20], Zc1,
        (const float*)d_in[22], (const float*)d_in[23], out);
}

// Round 17
// 315.252 us; speedup vs baseline: 1.1870x; 1.0394x over previous
//
#include <hip/hip_runtime.h>
#include <math.h>

#define CDIV(a, b) (((a) + (b) - 1) / (b))

#define LOG2E 1.4426950408889634f
#define SC5  (0.44721359549996f * LOG2E)
#define SC10 (0.31622776601684f * LOG2E)
#define SC21 (0.21821789023599f * LOG2E)
#define EXP2(x) __builtin_amdgcn_exp2f(x)

// ---------- fused 3x3 s2 conv + relu + qkv projection (layer 1 only) ----------
// q written padded [bh][n][DP]; K/V interleaved per row: kv[bh][n][2*DP] = K(DP)|V(DP).
template <int CIN, int HIN, int COUT, int HOUT, int INNER, int DP, int TPX>
__global__ void __launch_bounds__(256) conv_qkv(const float* __restrict__ in,
                                                const float* __restrict__ cw,
                                                const float* __restrict__ cb,
                                                const float* __restrict__ qw,
                                                const float* __restrict__ qb,
                                                float* __restrict__ z, float* __restrict__ q,
                                                float* __restrict__ kv) {
    constexpr int N = HOUT * HOUT;
    __shared__ float zt[COUT * TPX];
    const int b  = blockIdx.x / (N / TPX);
    const int n0 = (blockIdx.x % (N / TPX)) * TPX;
    const int tid = threadIdx.x;

    for (int idx = tid; idx < COUT * TPX; idx += 256) {
        int c = idx / TPX, px = idx % TPX;
        int n = n0 + px;
        int ho = n / HOUT, wo = n % HOUT;
        float acc = cb[c];
        for (int ci = 0; ci < CIN; ++ci) {
            const float* ip = in + (size_t)(b * CIN + ci) * HIN * HIN;
            const float* wp = cw + (size_t)(c * CIN + ci) * 9;
            #pragma unroll
            for (int kh = 0; kh < 3; ++kh) {
                int hi = 2 * ho + kh - 1;
                if (hi < 0 || hi >= HIN) continue;
                #pragma unroll
                for (int kw = 0; kw < 3; ++kw) {
                    int wi = 2 * wo + kw - 1;
                    if (wi < 0 || wi >= HIN) continue;
                    acc = fmaf(wp[kh * 3 + kw], ip[hi * HIN + wi], acc);
                }
            }
        }
        acc = fmaxf(acc, 0.f);
        zt[idx] = acc;
        z[((size_t)(b * COUT) + c) * N + n] = acc;
    }
    __syncthreads();

    constexpr int OC3 = 3 * INNER;
    for (int idx = tid; idx < OC3 * TPX; idx += 256) {
        int oc = idx / TPX, px = idx % TPX;
        float val = qb[oc];
        const float* wp = qw + (size_t)oc * COUT;
        #pragma unroll 8
        for (int c = 0; c < COUT; ++c) val = fmaf(wp[c], zt[c * TPX + px], val);
        int part = oc / INNER;
        int r = oc - part * INNER;
        int hh = r % 3, dd = r / 3;  // heads fastest
        size_t n = n0 + px;
        if (part == 0)
            q[((size_t)(b * 3 + hh) * N + n) * DP + dd] = val;
        else
            kv[((size_t)(b * 3 + hh) * N + n) * (2 * DP) + (part - 1) * DP + dd] = val;
    }
}

// ---------- fused: prev outproj(+residual) halo -> conv3x3 s2 relu -> qkv ----------
// Phase 0a stages the o1 slice (attention output, [bh][d][N1]) into LDS with coalesced
// loads ONCE; phase 0b computes outproj from LDS broadcasts (no scalar global chains).
template <int CPREV, int INNERP, int DPREV, int HINW, int COUT, int HOUT, int INNER, int DP, int TPX>
__global__ void __launch_bounds__(256) fused_oc(const float* __restrict__ o1,
                                                const float* __restrict__ ow,
                                                const float* __restrict__ ob,
                                                const float* __restrict__ zres,
                                                const float* __restrict__ cw,
                                                const float* __restrict__ cb,
                                                const float* __restrict__ qw,
                                                const float* __restrict__ qb,
                                                float* __restrict__ z, float* __restrict__ q,
                                                float* __restrict__ kv) {
    constexpr int N2 = HOUT * HOUT;
    constexpr int N1 = HINW * HINW;
    constexpr int TROWS = TPX / HOUT;     // output rows per tile
    constexpr int HR = 2 * TROWS + 1;     // halo input rows
    constexpr int HALO = HR * HINW;
    __shared__ float smem[INNERP * HALO + CPREV * HALO];
    float* o1s = smem;                    // INNERP*HALO (phase 0 only)
    float* zh  = smem + INNERP * HALO;    // CPREV*HALO
    float* zt  = smem;                    // COUT*TPX, overlays o1s after phase 0b
    const int b  = blockIdx.x / (N2 / TPX);
    const int n0 = (blockIdx.x % (N2 / TPX)) * TPX;
    const int tid = threadIdx.x;
    const int ho0 = n0 / HOUT;
    const int row0 = 2 * ho0 - 1;

    // phase 0a: stage o1 halo slice (coalesced; o1 row index = b*INNERP + (hh*DPREV+dd))
    for (int t = tid; t < INNERP * HALO; t += 256) {
        int hd = t / HALO, p = t - hd * HALO;
        int row = row0 + p / HINW;
        float v = 0.f;
        if (row >= 0 && row < HINW)
            v = o1[((size_t)(b * INNERP + hd)) * N1 + row * HINW + (p % HINW)];
        o1s[t] = v;
    }
    __syncthreads();

    // phase 0b: outproj + bias + residual for the halo -> zh (o1 reads now LDS)
    for (int t = tid; t < CPREV * HALO; t += 256) {
        int ci = t / HALO, p = t - ci * HALO;
        int row = row0 + p / HINW;
        float val = 0.f;  // conv zero-padding
        if (row >= 0 && row < HINW) {
            int n1 = row * HINW + (p % HINW);
            val = ob[ci] + zres[((size_t)(b * CPREV) + ci) * N1 + n1];
            const float* wp = ow + (size_t)ci * INNERP;
            for (int dd = 0; dd < DPREV; ++dd) {
                #pragma unroll
                for (int hh = 0; hh < 3; ++hh)
                    val = fmaf(wp[dd * 3 + hh], o1s[(hh * DPREV + dd) * HALO + p], val);
            }
        }
        zh[t] = val;
    }
    __syncthreads();

    // phase 1: conv from LDS halo (+ relu); zt overlays o1s (safe after barrier)
    for (int idx = tid; idx < COUT * TPX; idx += 256) {
        int c = idx / TPX, px = idx - (idx / TPX) * TPX;
        int hol = px / HOUT, wo = px - hol * HOUT;
        float acc = cb[c];
        for (int ci = 0; ci < CPREV; ++ci) {
            const float* zp = zh + ci * HALO;
            const float* wp = cw + (size_t)(c * CPREV + ci) * 9;
            #pragma unroll
            for (int kh = 0; kh < 3; ++kh) {
                int r = 2 * hol + kh;
                #pragma unroll
                for (int kw = 0; kw < 3; ++kw) {
                    int col = 2 * wo + kw - 1;
                    if (col < 0 || col >= HINW) continue;
                    acc = fmaf(wp[kh * 3 + kw], zp[r * HINW + col], acc);
                }
            }
        }
        acc = fmaxf(acc, 0.f);
        zt[idx] = acc;
        z[((size_t)(b * COUT) + c) * N2 + n0 + px] = acc;
    }
    __syncthreads();

    // phase 2: qkv from LDS tile
    constexpr int OC3 = 3 * INNER;
    for (int idx = tid; idx < OC3 * TPX; idx += 256) {
        int oc = idx / TPX, px = idx % TPX;
        float val = qb[oc];
        const float* wp = qw + (size_t)oc * COUT;
        #pragma unroll 8
        for (int c = 0; c < COUT; ++c) val = fmaf(wp[c], zt[c * TPX + px], val);
        int part = oc / INNER;
        int r = oc - part * INNER;
        int hh = r % 3, dd = r / 3;  // heads fastest
        size_t n = n0 + px;
        if (part == 0)
            q[((size_t)(b * 3 + hh) * N2 + n) * DP + dd] = val;
        else
            kv[((size_t)(b * 3 + hh) * N2 + n) * (2 * DP) + (part - 1) * DP + dd] = val;
    }
}

// ---------- attention (L1/L2): no-max softmax via native exp2; KV interleaved rows ----------
template <int D, int DP, int RPT, int PF, int NW>
__global__ void __launch_bounds__(NW * 64) attn_big(const float* __restrict__ q,
                                                    const float* __restrict__ kv,
                                                    const float* __restrict__ table,
                                                    float* __restrict__ o, int N, int log2Hg,
                                                    int T, float scale2) {
    extern __shared__ float smem[];
    float* tb = smem;    // T floats, pre-scaled by scale2 (incl. log2e)
    float* comb = smem;  // overlays tb after j-loop
    constexpr int BT = NW * 64;
    constexpr int ROWS = 64 * RPT;
    constexpr int CSTR = (D % 2 == 0) ? (D + 3) : (D + 2);
    constexpr int NV4 = DP / 4;
    constexpr int RV4 = 2 * NV4;

    const int bh = blockIdx.x % 96;
    const int chunk = blockIdx.x / 96;
    const int h = bh % 3;
    const int tid = threadIdx.x;
    const int wave = tid >> 6;
    const int lane = tid & 63;
    const int Hg = 1 << log2Hg;
    const int W2 = 2 * Hg - 1;
    const int base = chunk * ROWS;

    for (int t = tid; t < T; t += BT) tb[t] = table[t * 3 + h] * scale2;

    float qr[RPT][D];
    int ibase[RPT];
    #pragma unroll
    for (int r = 0; r < RPT; ++r) {
        int i = base + lane + 64 * r;
        const float* qg = q + ((size_t)bh * N + i) * DP;
        #pragma unroll
        for (int dd = 0; dd < D; ++dd) qr[r][dd] = qg[dd];
        ibase[r] = ((i >> log2Hg) + Hg - 1) * W2 + (i & (Hg - 1)) + Hg - 1;
    }
    __syncthreads();

    float acc[RPT][D];
    float lsum[RPT];
    #pragma unroll
    for (int r = 0; r < RPT; ++r) {
        lsum[r] = 0.f;
        #pragma unroll
        for (int dd = 0; dd < D; ++dd) acc[r][dd] = 0.f;
    }

    const float4* kvb = (const float4*)(kv + (size_t)bh * N * (2 * DP));
    const int NJ = N / NW;
    const int j0 = wave * NJ;

    float4 buf[PF][RV4];
    #pragma unroll
    for (int p = 0; p < PF; ++p)
        #pragma unroll
        for (int x = 0; x < RV4; ++x) buf[p][x] = kvb[(size_t)(j0 + p) * RV4 + x];

    for (int jj = 0; jj < NJ; jj += PF) {
        #pragma unroll
        for (int p = 0; p < PF; ++p) {
            const int j = j0 + jj + p;
            const float* kr = (const float*)&buf[p][0];
            const float* vr = kr + DP;
            const int joff = (j >> log2Hg) * W2 + (j & (Hg - 1));
            #pragma unroll
            for (int r = 0; r < RPT; ++r) {
                float s = 0.f;
                #pragma unroll
                for (int dd = 0; dd < D; ++dd) s = fmaf(qr[r][dd], kr[dd], s);
                float e = EXP2(fmaf(s, scale2, tb[ibase[r] - joff]));
                lsum[r] += e;
                #pragma unroll
                for (int dd = 0; dd < D; ++dd) acc[r][dd] = fmaf(e, vr[dd], acc[r][dd]);
            }
            #pragma unroll
            for (int x = 0; x < RV4; ++x) buf[p][x] = kvb[(size_t)(j + PF) * RV4 + x];
        }
    }

    __syncthreads();
    #pragma unroll
    for (int r = 0; r < RPT; ++r) {
        float* cp = comb + (size_t)(wave * ROWS + lane + 64 * r) * CSTR;
        #pragma unroll
        for (int dd = 0; dd < D; ++dd) cp[dd] = acc[r][dd];
        cp[D] = lsum[r];
    }
    __syncthreads();
    if (tid < ROWS) {
        float af[D];
        #pragma unroll
        for (int dd = 0; dd < D; ++dd) af[dd] = 0.f;
        float lf = 0.f;
        #pragma unroll
        for (int wv = 0; wv < NW; ++wv) {
            const float* cp = comb + (size_t)(wv * ROWS + tid) * CSTR;
            #pragma unroll
            for (int dd = 0; dd < D; ++dd) af[dd] += cp[dd];
            lf += cp[D];
        }
        float inv = 1.0f / lf;
        int i = base + tid;
        #pragma unroll
        for (int dd = 0; dd < D; ++dd)
            o[((size_t)bh * D + dd) * N + i] = af[dd] * inv;  // O layout [bh][d][N]
    }
}

// ---------- L3 attention: one block per bh; KV+table staged in LDS; 4-wave j-split ----------
__global__ void __launch_bounds__(256) attn_small(const float* __restrict__ q,
                                                  const float* __restrict__ kv,
                                                  const float* __restrict__ table,
                                                  float* __restrict__ o, float scale2) {
    constexpr int D = 21, DP = 24, NN = 64;
    constexpr int CSTR = 23;
    __shared__ float smem[4 * NN * CSTR];  // 23552 B; comb overlays kvs/tb
    float* kvs = smem;
    float* tb = kvs + NN * 2 * DP;
    float* comb = smem;

    const int bh = blockIdx.x;     // 96 blocks
    const int h = bh % 3;
    const int tid = threadIdx.x;
    const int wave = tid >> 6;
    const int lane = tid & 63;

    {
        const float4* kvg = (const float4*)(kv + (size_t)bh * NN * 2 * DP);
        float4* kvs4 = (float4*)kvs;
        for (int t = tid; t < NN * 2 * DP / 4; t += 256) kvs4[t] = kvg[t];
        for (int t = tid; t < 225; t += 256) tb[t] = table[t * 3 + h] * scale2;
    }

    const int i = lane;
    const float* qg = q + ((size_t)bh * NN + i) * DP;
    float qr[D];
    #pragma unroll
    for (int dd = 0; dd < D; ++dd) qr[dd] = qg[dd];
    const int ibase = ((i >> 3) + 7) * 15 + (i & 7) + 7;
    __syncthreads();

    float acc[D];
    #pragma unroll
    for (int dd = 0; dd < D; ++dd) acc[dd] = 0.f;
    float lsum = 0.f;

    const int j0 = wave * 16;
    #pragma unroll
    for (int jj = 0; jj < 16; ++jj) {
        const int j = j0 + jj;
        float4 r4[12];
        const float4* rp = (const float4*)(kvs + j * 2 * DP);
        #pragma unroll
        for (int x = 0; x < 12; ++x) r4[x] = rp[x];
        const float* kr = (const float*)r4;
        const float* vr = kr + DP;
        const int joff = (j >> 3) * 15 + (j & 7);
        float s = 0.f;
        #pragma unroll
        for (int dd = 0; dd < D; ++dd) s = fmaf(qr[dd], kr[dd], s);
        float e = EXP2(fmaf(s, scale2, tb[ibase - joff]));
        lsum += e;
        #pragma unroll
        for (int dd = 0; dd < D; ++dd) acc[dd] = fmaf(e, vr[dd], acc[dd]);
    }

    __syncthreads();
    {
        float* cp = comb + (size_t)(wave * NN + lane) * CSTR;
        #pragma unroll
        for (int dd = 0; dd < D; ++dd) cp[dd] = acc[dd];
        cp[D] = lsum;
    }
    __syncthreads();
    if (tid < NN) {
        float af[D];
        #pragma unroll
        for (int dd = 0; dd < D; ++dd) af[dd] = 0.f;
        float lf = 0.f;
        #pragma unroll
        for (int wv = 0; wv < 4; ++wv) {
            const float* cp = comb + (size_t)(wv * NN + tid) * CSTR;
            #pragma unroll
            for (int dd = 0; dd < D; ++dd) af[dd] += cp[dd];
            lf += cp[D];
        }
        float inv = 1.0f / lf;
        #pragma unroll
        for (int dd = 0; dd < D; ++dd)
            o[((size_t)bh * D + dd) * NN + tid] = af[dd] * inv;
    }
}

// ---------- tail: outproj3 + global-avg-pool + classifier, one block per batch ----------
// o slice for this batch staged in LDS first (one contiguous 16 KB coalesced copy).
__global__ void __launch_bounds__(256) tail(const float* __restrict__ o,
                                            const float* __restrict__ ow,
                                            const float* __restrict__ ob,
                                            const float* __restrict__ zin,
                                            const float* __restrict__ cw,
                                            const float* __restrict__ cb,
                                            float* __restrict__ out) {
    __shared__ float os[63 * 64];
    __shared__ float zt[64 * 65];
    __shared__ float p[64];
    const int b = blockIdx.x;
    const int tid = threadIdx.x;
    // stage o[b]: rows b*63..b*63+62 are contiguous (layout [bh][d][N], hd = hh*21+dd)
    for (int t = tid; t < 63 * 64; t += 256) os[t] = o[(size_t)(b * 63) * 64 + t];
    __syncthreads();
    for (int idx = tid; idx < 64 * 64; idx += 256) {
        int c = idx >> 6, n = idx & 63;
        float val = ob[c] + zin[((size_t)(b * 64) + c) * 64 + n];
        const float* wp = ow + (size_t)c * 63;
        for (int dd = 0; dd < 21; ++dd) {
            #pragma unroll
            for (int hh = 0; hh < 3; ++hh)
                val = fmaf(wp[dd * 3 + hh], os[(hh * 21 + dd) * 64 + n], val);
        }
        zt[c * 65 + n] = val;
    }
    __syncthreads();
    if (tid < 64) {
        float s = 0.f;
        #pragma unroll
        for (int n = 0; n < 64; ++n) s += zt[tid * 65 + n];
        s *= (1.0f / 64.0f);
        p[tid] = s;
        out[b * 64 + tid] = s;
    }
    __syncthreads();
    if (tid < 10) {
        float val = cb[tid];
        const float* wp = cw + (size_t)tid * 64;
        #pragma unroll
        for (int kk = 0; kk < 64; ++kk) val = fmaf(wp[kk], p[kk], val);
        out[2048 + b * 10 + tid] = val;
    }
}

extern "C" void kernel_launch(void* const* d_in, const int* in_sizes, int n_in,
                              void* d_out, int out_size, void* d_ws, size_t ws_size,
                              hipStream_t stream) {
    float* ws = (float*)d_ws;
    float* Zc1 = ws;                 // conv1 z (524288) / later conv3 z (131072)
    float* Zc2 = Zc1 + 524288;       // conv2 z (262144)
    float* Q   = Zc2 + 262144;       // 786432 (96*1024*8 max)
    float* KV  = Q + 786432;         // 1572864 (96*1024*16 max)
    float* O   = KV + 1572864;       // 491520 (96*1024*5 max)

    float* out = (float*)d_out;

    // ===== layer 1: Cin=1 H64->32, dim=16, inner=15, d=5 (DP=8), N=1024, Hg=32 =====
    conv_qkv<1, 64, 16, 32, 15, 8, 64><<<32 * 16, 256, 0, stream>>>(
        (const float*)d_in[0], (const float*)d_in[1], (const float*)d_in[2],
        (const float*)d_in[3], (const float*)d_in[4], Zc1, Q, KV);
    attn_big<5, 8, 2, 2, 4><<<96 * 8, 256, 15876, stream>>>(
        Q, KV, (const float*)d_in[7], O, 1024, 5, 3969, SC5);

    // ===== layer 2 (fused outproj1 + conv2 + qkv2): dim=32, inner=30, d=10 (DP=12), N=256 =====
    fused_oc<16, 15, 5, 32, 32, 16, 30, 12, 32><<<32 * 8, 256, 0, stream>>>(
        O, (const float*)d_in[5], (const float*)d_in[6], Zc1,
        (const float*)d_in[8], (const float*)d_in[9],
        (const float*)d_in[10], (const float*)d_in[11], Zc2, Q, KV);
    attn_big<10, 12, 1, 2, 4><<<96 * 4, 256, 13312, stream>>>(
        Q, KV, (const float*)d_in[14], O, 256, 4, 961, SC10);

    // ===== layer 3 (fused outproj2 + conv3 + qkv3): dim=64, inner=63, d=21 (DP=24), N=64 =====
    fused_oc<32, 30, 10, 16, 64, 8, 63, 24, 8><<<32 * 8, 256, 0, stream>>>(
        O, (const float*)d_in[12], (const float*)d_in[13], Zc2,
        (const float*)d_in[15], (const float*)d_in[16],
        (const float*)d_in[17], (const float*)d_in[18], Zc1, Q, KV);
    attn_small<<<96, 256, 0, stream>>>(Q, KV, (const float*)d_in[21], O, SC21);

    // ===== head =====
    tail<<<32, 256, 0, stream>>>(
        O, (const float*)d_in[19], (const float*)d_in[20], Zc1,
        (const float*)d_in[22], (const float*)d_in[23], out);
}